// Round 15
// baseline (136.893 us; speedup 1.0000x reference)
//
#include <hip/hip_runtime.h>
#include <math.h>

#define NN 1600      // H*W
#define BB 8         // batch
#define CC 64        // channels
#define KK 10        // top-k
#define ROWS (BB*NN) // 12800
#define EPB (NN*KK)  // edge-memberships per batch = 16000
#define GE 16        // memberships per wave in gather2

// ---------------------------------------------------------------------------
// Kernel 1: fused {zero Acc1+Acc2+DV+done_ctr+out} (blocks < 1600) and
// conv_relu pre[b,n] = relu(sum_c x[b,c,n]*w[c] + b0) (blocks >= 1600).
// ---------------------------------------------------------------------------
__global__ void zeroconv_kernel(float4* __restrict__ accs, int n4,
                                int4* __restrict__ DV4, float* __restrict__ out,
                                int* __restrict__ done_ctr,
                                const float* __restrict__ x, const float* __restrict__ w,
                                const float* __restrict__ bsc, float* __restrict__ pre) {
    int blk = blockIdx.x, tid = threadIdx.x;
    if (blk < 1600) {
        int gid = blk * 256 + tid;
        if (gid < n4) accs[gid] = make_float4(0.f, 0.f, 0.f, 0.f);
        if (gid < ROWS / 4) DV4[gid] = make_int4(0, 0, 0, 0);
        if (gid < BB) { out[gid] = 0.f; done_ctr[gid] = 0; }
    } else {
        int gid = (blk - 1600) * 256 + tid;
        if (gid >= ROWS) return;
        int b = gid / NN, n = gid % NN;
        const float* xb = x + (size_t)b * CC * NN;
        float acc = bsc[0];
#pragma unroll 16
        for (int c = 0; c < CC; ++c) acc = fmaf(xb[(size_t)c * NN + n], w[c], acc);
        pre[gid] = fmaxf(acc, 0.f);
    }
}

// ---------------------------------------------------------------------------
// Kernel 2: xx[b,:] = softmax(pre[b,:])
// ---------------------------------------------------------------------------
__global__ void softmax_kernel(const float* __restrict__ pre, float* __restrict__ xx) {
    __shared__ float xs[NN];
    __shared__ float red[256];
    int b = blockIdx.x, tid = threadIdx.x;
    for (int n = tid; n < NN; n += 256) xs[n] = pre[b * NN + n];
    __syncthreads();
    float m = -1e30f;
    for (int n = tid; n < NN; n += 256) m = fmaxf(m, xs[n]);
    red[tid] = m; __syncthreads();
    for (int s = 128; s > 0; s >>= 1) { if (tid < s) red[tid] = fmaxf(red[tid], red[tid + s]); __syncthreads(); }
    float mx = red[0]; __syncthreads();
    float ls = 0.f;
    for (int n = tid; n < NN; n += 256) { float e = expf(xs[n] - mx); xs[n] = e; ls += e; }
    red[tid] = ls; __syncthreads();
    for (int s = 128; s > 0; s >>= 1) { if (tid < s) red[tid] += red[tid + s]; __syncthreads(); }
    float S = red[0];
    for (int n = tid; n < NN; n += 256) xx[b * NN + n] = xs[n] / S;
}

// ---------------------------------------------------------------------------
// Kernel 3: rank-by-count "sort" (bit-identical to a stable (value,idx) sort).
// ---------------------------------------------------------------------------
__global__ void __launch_bounds__(256) rank_kernel(const float* __restrict__ xx,
                                                   float* __restrict__ sval, int* __restrict__ sidx,
                                                   int* __restrict__ gst, int* __restrict__ gen,
                                                   int* __restrict__ pos) {
    __shared__ float xs[NN];
    int tid = threadIdx.x;
    int wid = tid >> 6, lane = tid & 63;
    int row = blockIdx.x * 4 + wid;     // all 4 rows share one batch
    int b = row / NN, i = row % NN;
    for (int t = tid; t < NN; t += 256) xs[t] = xx[b * NN + t];
    __syncthreads();
    float xi = xs[i];
    int strict = 0, eq_total = 0, eq_before = 0;
#pragma unroll 5
    for (int s = 0; s < 25; ++s) {
        int j = lane + 64 * s;
        float vj = xs[j];
        unsigned long long blt = __ballot(vj < xi);
        unsigned long long beq = __ballot(vj == xi);
        unsigned long long bbf = __ballot(vj == xi && j < i);
        strict    += __popcll(blt);
        eq_total  += __popcll(beq);
        eq_before += __popcll(bbf);
    }
    if (lane == 0) {
        int rank = strict + eq_before;
        sval[b * NN + rank] = xi;
        sidx[b * NN + rank] = i;
        gst[b * NN + rank] = strict;
        gen[b * NN + rank] = strict + eq_total;
        pos[b * NN + i] = rank;
    }
}

// ---------------------------------------------------------------------------
// Kernel 4: walk the sorted array -> exact stable top-10 per row + DV,
// PLUS fused per-batch scan: the LAST of each batch's 25 blocks (device-scope
// acq_rel ticket) computes the exclusive scan of DV -> cursor and dv2.
// DV reads in the scan use agent-scope atomic loads (per-XCD L2 is not
// coherent for plain loads of atomically-updated lines). cursor/dv2 cross a
// kernel boundary afterwards, so the dispatch-end flush covers consumers.
// ---------------------------------------------------------------------------
__global__ void __launch_bounds__(256) walk_kernel(const float* __restrict__ sval,
                                                   const int* __restrict__ sidx,
                                                   const int* __restrict__ gst,
                                                   const int* __restrict__ gen,
                                                   const int* __restrict__ pos,
                                                   int* __restrict__ topk, int* __restrict__ DV,
                                                   int* __restrict__ done_ctr,
                                                   int* __restrict__ cursor,
                                                   float* __restrict__ dv2) {
    __shared__ float val[NN];
    __shared__ int   idx[NN];
    __shared__ int   gs[NN];
    __shared__ int   ge[NN];
    __shared__ int   hist[NN];
    __shared__ int   sums[256];
    __shared__ int   ticket;
    int blk = blockIdx.x;
    int b = blk / 25, chunk = blk % 25;
    int tid = threadIdx.x;
    for (int p = tid; p < NN; p += 256) {
        val[p] = sval[b * NN + p];
        idx[p] = sidx[b * NN + p];
        gs[p]  = gst[b * NN + p];
        ge[p]  = gen[b * NN + p];
        hist[p] = 0;
    }
    __syncthreads();
    int win[KK];
    int wid = tid >> 6, lane = tid & 63;
    bool active = lane < 16;
    int i = chunk * 64 + wid * 16 + lane;
    if (active) {
        int p = pos[b * NN + i];
        float xi = val[p];
        int g0 = gs[p], g1 = ge[p];
        if (g1 - g0 >= KK) {
#pragma unroll
            for (int r = 0; r < KK; ++r) win[r] = idx[g0 + r];
            bool in_top = (p - g0) < KK;
            if (!in_top) win[KK - 1] = i;
        } else {
            int cnt = 0;
            for (int q = g0; q < g1; ++q) win[cnt++] = idx[q];
            int L = g0 - 1, R = g1;
            while (cnt < KK) {
                float dL = (L >= 0) ? xi - val[L] : __builtin_inff();
                float dR = (R < NN) ? val[R] - xi : __builtin_inff();
                float dm = fminf(dL, dR);
                int La = NN, Lb = -1, Ra = NN, Rb = -1;
                if (dL == dm) {
                    Lb = L; La = gs[L];
                    while (La - 1 >= 0 && (xi - val[La - 1]) == dm) La = gs[La - 1];
                }
                if (dR == dm) {
                    Ra = R; Rb = ge[R] - 1;
                    while (Rb + 1 < NN && (val[Rb + 1] - xi) == dm) Rb = ge[Rb + 1] - 1;
                }
                bool oneL = (Lb >= 0) && (Rb < 0) && (La == gs[Lb]);
                bool oneR = (Rb >= 0) && (Lb < 0) && (Rb == ge[Ra] - 1);
                if (oneL) {
                    for (int q = La; q <= Lb && cnt < KK; ++q) win[cnt++] = idx[q];
                } else if (oneR) {
                    for (int q = Ra; q <= Rb && cnt < KK; ++q) win[cnt++] = idx[q];
                } else {
                    int last = -1;
                    while (cnt < KK) {
                        int best = 0x7fffffff;
                        for (int q = La; q <= Lb; ++q) { int jj = idx[q]; if (jj > last && jj < best) best = jj; }
                        for (int q = Ra; q <= Rb; ++q) { int jj = idx[q]; if (jj > last && jj < best) best = jj; }
                        if (best == 0x7fffffff) break;
                        win[cnt++] = best; last = best;
                    }
                }
                if (Lb >= 0) L = La - 1;
                if (Rb >= 0) R = Rb + 1;
            }
        }
#pragma unroll
        for (int r = 0; r < KK; ++r) {
            topk[(size_t)(b * NN + i) * KK + r] = win[r];
            atomicAdd(&hist[win[r]], 1);
        }
    }
    __syncthreads();
    for (int p = tid; p < NN; p += 256) {
        int h = hist[p];
        if (h) atomicAdd(&DV[b * NN + p], h);
    }
    // ---- fused per-batch scan: last block of this batch's 25 does it ----
    __threadfence();
    if (tid == 0)
        ticket = __hip_atomic_fetch_add(&done_ctr[b], 1, __ATOMIC_ACQ_REL,
                                        __HIP_MEMORY_SCOPE_AGENT);
    __syncthreads();
    if (ticket == 24) {           // block-uniform (shared) condition
        int loc[7], dvv[7]; int s = 0;
#pragma unroll
        for (int e = 0; e < 7; ++e) {
            int p = tid * 7 + e;
            int v = 0;
            if (p < NN)
                v = __hip_atomic_load(&DV[b * NN + p], __ATOMIC_RELAXED,
                                      __HIP_MEMORY_SCOPE_AGENT);
            dvv[e] = v; loc[e] = s; s += v;
        }
        sums[tid] = s;
        __syncthreads();
        for (int off = 1; off < 256; off <<= 1) {
            int v = (tid >= off) ? sums[tid - off] : 0;
            __syncthreads();
            sums[tid] += v;
            __syncthreads();
        }
        int base = ((tid > 0) ? sums[tid - 1] : 0) + b * EPB;
#pragma unroll
        for (int e = 0; e < 7; ++e) {
            int p = tid * 7 + e;
            if (p < NN) {
                cursor[b * NN + p] = base + loc[e];
                dv2[b * NN + p] = 1.0f / sqrtf((float)dvv[e]);
            }
        }
    }
}

// ---------------------------------------------------------------------------
// Kernel 5: fused {CSR fill (blocks 0..499)} and {lin layer-1 (blocks 500..899)}.
// ---------------------------------------------------------------------------
__global__ void __launch_bounds__(256) filllin_kernel(const int* __restrict__ topk,
                                                      int* __restrict__ cursor,
                                                      int* __restrict__ inv_pack,
                                                      const float* __restrict__ in,
                                                      const float* __restrict__ W,
                                                      const float* __restrict__ bias,
                                                      const float* __restrict__ dv2,
                                                      float* __restrict__ outP) {
    __shared__ float Wl[CC * CC];
    __shared__ float bl[CC];
    int blk = blockIdx.x, tid = threadIdx.x;
    if (blk < 500) {
        // ---- CSR fill: inv_pack[slot] = (vertex<<17)|edge ----
        int gid = blk * 256 + tid;
        if (gid < ROWS * KK) {
            int row = gid / KK;          // global edge id
            int b = row / NN;
            int v = b * NN + topk[gid];  // global vertex id
            int slot = atomicAdd(&cursor[v], 1);
            inv_pack[slot] = (v << 17) | row;
        }
        return;
    }
    // ---- lin layer 1 (transform=0): P[row,c] = 0.1*dv2[row]*(x_row@W + b)[c]
    for (int t = tid; t < CC * CC; t += 256) Wl[t] = W[t];
    if (tid < CC) bl[tid] = bias[tid];
    __syncthreads();
    int lane = tid & 63, wid = tid >> 6;
    int gw = (blk - 500) * 4 + wid;
    int nw = 400 * 4;
    for (int row = gw; row < ROWS; row += nw) {
        float d = dv2[row];
        float vin = in[(size_t)row * CC + lane];
        int vbits = __float_as_int(vin);
        float acc = bl[lane];
#pragma unroll
        for (int kk = 0; kk < CC; ++kk) {
            float xv = __int_as_float(__builtin_amdgcn_readlane(vbits, kk));
            acc = fmaf(xv, Wl[kk * CC + lane], acc);
        }
        outP[(size_t)row * CC + lane] = 0.1f * d * acc;
    }
}

// ---------------------------------------------------------------------------
// Kernel 6: P[row,c] = 0.1 * dv2[row] * ( in_row @ W + bias )[c]
// transform=1: in_row[c] := relu(dv2[row] * in[row,c])   (layer 2)
// ---------------------------------------------------------------------------
__global__ void __launch_bounds__(256) lin_kernel(const float* __restrict__ in,
                                                  const float* __restrict__ W,
                                                  const float* __restrict__ bias,
                                                  const float* __restrict__ dv2,
                                                  float* __restrict__ outP, int transform) {
    __shared__ float Wl[CC * CC];
    __shared__ float bl[CC];
    int tid = threadIdx.x;
    for (int t = tid; t < CC * CC; t += 256) Wl[t] = W[t];
    if (tid < CC) bl[tid] = bias[tid];
    __syncthreads();
    int lane = tid & 63, wid = tid >> 6;
    int gw = blockIdx.x * 4 + wid;
    int nw = gridDim.x * 4;
    for (int row = gw; row < ROWS; row += nw) {
        float d = dv2[row];
        float vin = in[(size_t)row * CC + lane];
        if (transform) vin = fmaxf(d * vin, 0.f);
        int vbits = __float_as_int(vin);
        float acc = bl[lane];
#pragma unroll
        for (int kk = 0; kk < CC; ++kk) {
            float xv = __int_as_float(__builtin_amdgcn_readlane(vbits, kk));
            acc = fmaf(xv, Wl[kk * CC + lane], acc);
        }
        outP[(size_t)row * CC + lane] = 0.1f * d * acc;
    }
}

// ---------------------------------------------------------------------------
// Kernel 7: z[e,c] = sum_t P[v_t(e), c]   (pure gather, one wave per edge)
// ---------------------------------------------------------------------------
__global__ void __launch_bounds__(256) zedge_kernel(const float* __restrict__ P,
                                                    const int* __restrict__ topk,
                                                    float* __restrict__ z) {
    int wid = threadIdx.x >> 6, lane = threadIdx.x & 63;
    int e = blockIdx.x * 4 + wid;
    if (e >= ROWS) return;
    int b = e / NN;
    const int* tk = topk + e * KK;
    int v[KK];
#pragma unroll
    for (int t = 0; t < KK; ++t) v[t] = tk[t];
    float acc = 0.f;
#pragma unroll
    for (int t = 0; t < KK; ++t) acc += P[((size_t)b * NN + v[t]) * CC + lane];
    z[(size_t)e * CC + lane] = acc;
}

// ---------------------------------------------------------------------------
// Kernel 8: flat segmented gather over the CSR membership list (GE=16).
// ---------------------------------------------------------------------------
__global__ void __launch_bounds__(256) gather2_kernel(const float* __restrict__ z,
                                                      const int* __restrict__ inv_pack,
                                                      float* __restrict__ Acc) {
    int wid = threadIdx.x >> 6, lane = threadIdx.x & 63;
    int w = blockIdx.x * 4 + wid;          // 0..7999
    int base = w * GE;
    int pk_l = inv_pack[base + (lane & 15)];
    int eid[GE], own[GE];
#pragma unroll
    for (int t = 0; t < GE; ++t) {
        int pk = __builtin_amdgcn_readlane(pk_l, t);
        eid[t] = pk & 0x1ffff;
        own[t] = pk >> 17;
    }
    float val[GE];
#pragma unroll
    for (int t = 0; t < GE; ++t) val[t] = z[(size_t)eid[t] * CC + lane];
    float acc = val[0];
    int cur = own[0];
#pragma unroll
    for (int t = 1; t < GE; ++t) {
        if (own[t] != cur) {                // wave-uniform branch
            atomicAdd(&Acc[(size_t)cur * CC + lane], acc);
            cur = own[t]; acc = val[t];
        } else acc += val[t];
    }
    atomicAdd(&Acc[(size_t)cur * CC + lane], acc);
}

// ---------------------------------------------------------------------------
// Kernel 9: final conv + relu + per-batch sum. (out pre-zeroed)
// ---------------------------------------------------------------------------
__global__ void final_kernel(const float* __restrict__ Acc, const float* __restrict__ dv2,
                             const float* __restrict__ w, const float* __restrict__ bsc,
                             float* __restrict__ out) {
    __shared__ float red[256];
    int blk = blockIdx.x;
    int b = blk >> 3, chunk = blk & 7;
    int tid = threadIdx.x;
    float local = 0.f;
    if (tid < 200) {
        int n = chunk * 200 + tid;
        int q = n >> 6, r = n & 63;
        float acc = bsc[0];
#pragma unroll 8
        for (int c = 0; c < CC; ++c) {
            int rowl = c * 25 + q;
            float v = Acc[((size_t)b * NN + rowl) * CC + r];
            float h = fmaxf(dv2[b * NN + rowl] * v, 0.f);
            acc = fmaf(h, w[c], acc);
        }
        local = fmaxf(acc, 0.f);
    }
    red[tid] = local; __syncthreads();
    for (int s = 128; s > 0; s >>= 1) { if (tid < s) red[tid] += red[tid + s]; __syncthreads(); }
    if (tid == 0) atomicAdd(&out[b], red[0]);
}

// ---------------------------------------------------------------------------
extern "C" void kernel_launch(void* const* d_in, const int* in_sizes, int n_in,
                              void* d_out, int out_size, void* d_ws, size_t ws_size,
                              hipStream_t stream) {
    const float* x      = (const float*)d_in[0];
    const float* w_con1 = (const float*)d_in[1];
    const float* b_con1 = (const float*)d_in[2];
    const float* W1     = (const float*)d_in[3];
    const float* b1     = (const float*)d_in[4];
    const float* W2     = (const float*)d_in[5];
    const float* b2     = (const float*)d_in[6];
    const float* w_con2 = (const float*)d_in[7];
    const float* b_con2 = (const float*)d_in[8];

    char* ws = (char*)d_ws;
    float* xx       = (float*)(ws + 0);         //  51200
    float* dv2      = (float*)(ws + 51200);     //  51200
    int*   DV       = (int*)  (ws + 102400);    //  51200
    float* pre      = (float*)(ws + 153600);    //  51200 (cursor aliases after softmax/rank)
    int*   cursor   = (int*)  (ws + 153600);
    int*   topk     = (int*)  (ws + 204800);    // 512000
    float* buf0     = (float*)(ws + 716800);    // 3276800
    float* buf1     = (float*)(ws + 3993600);   // 3276800
    int*   inv_pack = (int*)  (ws + 7270400);   // 512000
    float* buf2     = (float*)(ws + 7782400);   // 3276800 (Acc1, pre-zeroed)
    float* buf3     = (float*)(ws + 11059200);  // 3276800 (Acc2, pre-zeroed)
    int*   done_ctr = (int*)  (ws + 14336000);  // 32 (per-batch tickets, pre-zeroed)
    // sort scratch aliases buf0 (dead before lin1):
    float* sval = (float*)(ws + 716800);
    int*   sidx = (int*)  (ws + 716800 + 51200);
    int*   gst  = (int*)  (ws + 716800 + 102400);
    int*   gen  = (int*)  (ws + 716800 + 153600);
    int*   pos  = (int*)  (ws + 716800 + 204800);

    float* out = (float*)d_out;

    // Fused: zero Acc1+Acc2 (409600 float4), DV, done_ctr, out + conv_relu -> pre.
    zeroconv_kernel<<<1650, 256, 0, stream>>>((float4*)buf2, 409600, (int4*)DV, out,
                                              done_ctr, x, w_con1, b_con1, pre);
    softmax_kernel<<<BB, 256, 0, stream>>>(pre, xx);

    rank_kernel<<<ROWS / 4, 256, 0, stream>>>(xx, sval, sidx, gst, gen, pos);
    // walk + fused per-batch scan (last-block-done) -> topk, DV, cursor, dv2
    walk_kernel<<<200, 256, 0, stream>>>(sval, sidx, gst, gen, pos, topk, DV,
                                         done_ctr, cursor, dv2);

    // Fused: CSR fill (500 blocks) + lin layer-1 (400 blocks) -> P1=buf0
    filllin_kernel<<<900, 256, 0, stream>>>(topk, cursor, inv_pack,
                                            x, W1, b1, dv2, buf0);

    // Layer 1: z1=buf1, Acc1=buf2
    zedge_kernel<<<ROWS / 4, 256, 0, stream>>>(buf0, topk, buf1);
    gather2_kernel<<<(ROWS * KK / GE) / 4, 256, 0, stream>>>(buf1, inv_pack, buf2);

    // Layer 2: P2=buf0, z2=buf1, Acc2=buf3
    lin_kernel<<<400, 256, 0, stream>>>(buf2, W2, b2, dv2, buf0, 1);
    zedge_kernel<<<ROWS / 4, 256, 0, stream>>>(buf0, topk, buf1);
    gather2_kernel<<<(ROWS * KK / GE) / 4, 256, 0, stream>>>(buf1, inv_pack, buf3);

    final_kernel<<<64, 256, 0, stream>>>(buf3, dv2, w_con2, b_con2, out);
}

// Round 16
// 122.171 us; speedup vs baseline: 1.1205x; 1.1205x over previous
//
#include <hip/hip_runtime.h>
#include <math.h>

#define NN 1600      // H*W
#define BB 8         // batch
#define CC 64        // channels
#define KK 10        // top-k
#define ROWS (BB*NN) // 12800
#define EPB (NN*KK)  // edge-memberships per batch = 16000
#define GE 16        // memberships per wave in gather2

// ---------------------------------------------------------------------------
// Kernel 1: fused {zero Acc1+Acc2+DV+out} (blocks < 1600) and
// conv_relu pre[b,n] = relu(sum_c x[b,c,n]*w[c] + b0) (blocks >= 1600).
// ---------------------------------------------------------------------------
__global__ void zeroconv_kernel(float4* __restrict__ accs, int n4,
                                int4* __restrict__ DV4, float* __restrict__ out,
                                const float* __restrict__ x, const float* __restrict__ w,
                                const float* __restrict__ bsc, float* __restrict__ pre) {
    int blk = blockIdx.x, tid = threadIdx.x;
    if (blk < 1600) {
        int gid = blk * 256 + tid;
        if (gid < n4) accs[gid] = make_float4(0.f, 0.f, 0.f, 0.f);
        if (gid < ROWS / 4) DV4[gid] = make_int4(0, 0, 0, 0);
        if (gid < BB) out[gid] = 0.f;
    } else {
        int gid = (blk - 1600) * 256 + tid;
        if (gid >= ROWS) return;
        int b = gid / NN, n = gid % NN;
        const float* xb = x + (size_t)b * CC * NN;
        float acc = bsc[0];
#pragma unroll 16
        for (int c = 0; c < CC; ++c) acc = fmaf(xb[(size_t)c * NN + n], w[c], acc);
        pre[gid] = fmaxf(acc, 0.f);
    }
}

// ---------------------------------------------------------------------------
// Kernel 2: xx[b,:] = softmax(pre[b,:])
// ---------------------------------------------------------------------------
__global__ void softmax_kernel(const float* __restrict__ pre, float* __restrict__ xx) {
    __shared__ float xs[NN];
    __shared__ float red[256];
    int b = blockIdx.x, tid = threadIdx.x;
    for (int n = tid; n < NN; n += 256) xs[n] = pre[b * NN + n];
    __syncthreads();
    float m = -1e30f;
    for (int n = tid; n < NN; n += 256) m = fmaxf(m, xs[n]);
    red[tid] = m; __syncthreads();
    for (int s = 128; s > 0; s >>= 1) { if (tid < s) red[tid] = fmaxf(red[tid], red[tid + s]); __syncthreads(); }
    float mx = red[0]; __syncthreads();
    float ls = 0.f;
    for (int n = tid; n < NN; n += 256) { float e = expf(xs[n] - mx); xs[n] = e; ls += e; }
    red[tid] = ls; __syncthreads();
    for (int s = 128; s > 0; s >>= 1) { if (tid < s) red[tid] += red[tid + s]; __syncthreads(); }
    float S = red[0];
    for (int n = tid; n < NN; n += 256) xx[b * NN + n] = xs[n] / S;
}

// ---------------------------------------------------------------------------
// Kernel 3: rank-by-count "sort" (bit-identical to a stable (value,idx) sort).
// ---------------------------------------------------------------------------
__global__ void __launch_bounds__(256) rank_kernel(const float* __restrict__ xx,
                                                   float* __restrict__ sval, int* __restrict__ sidx,
                                                   int* __restrict__ gst, int* __restrict__ gen,
                                                   int* __restrict__ pos) {
    __shared__ float xs[NN];
    int tid = threadIdx.x;
    int wid = tid >> 6, lane = tid & 63;
    int row = blockIdx.x * 4 + wid;     // all 4 rows share one batch
    int b = row / NN, i = row % NN;
    for (int t = tid; t < NN; t += 256) xs[t] = xx[b * NN + t];
    __syncthreads();
    float xi = xs[i];
    int strict = 0, eq_total = 0, eq_before = 0;
#pragma unroll 5
    for (int s = 0; s < 25; ++s) {
        int j = lane + 64 * s;
        float vj = xs[j];
        unsigned long long blt = __ballot(vj < xi);
        unsigned long long beq = __ballot(vj == xi);
        unsigned long long bbf = __ballot(vj == xi && j < i);
        strict    += __popcll(blt);
        eq_total  += __popcll(beq);
        eq_before += __popcll(bbf);
    }
    if (lane == 0) {
        int rank = strict + eq_before;
        sval[b * NN + rank] = xi;
        sidx[b * NN + rank] = i;
        gst[b * NN + rank] = strict;
        gen[b * NN + rank] = strict + eq_total;
        pos[b * NN + i] = rank;
    }
}

// ---------------------------------------------------------------------------
// Kernel 4: walk the sorted array -> exact stable top-10 per row + DV.
// 400 blocks = 50 chunks x 8 batches; 32 rows/block across 4 waves
// (8 active lanes/wave): halves the per-wave divergence tail vs 16.
// ---------------------------------------------------------------------------
__global__ void __launch_bounds__(256) walk_kernel(const float* __restrict__ sval,
                                                   const int* __restrict__ sidx,
                                                   const int* __restrict__ gst,
                                                   const int* __restrict__ gen,
                                                   const int* __restrict__ pos,
                                                   int* __restrict__ topk, int* __restrict__ DV) {
    __shared__ float val[NN];
    __shared__ int   idx[NN];
    __shared__ int   gs[NN];
    __shared__ int   ge[NN];
    __shared__ int   hist[NN];
    int blk = blockIdx.x;
    int b = blk / 50, chunk = blk % 50;
    int tid = threadIdx.x;
    for (int p = tid; p < NN; p += 256) {
        val[p] = sval[b * NN + p];
        idx[p] = sidx[b * NN + p];
        gs[p]  = gst[b * NN + p];
        ge[p]  = gen[b * NN + p];
        hist[p] = 0;
    }
    __syncthreads();
    int win[KK];
    int wid = tid >> 6, lane = tid & 63;
    bool active = lane < 8;
    int i = chunk * 32 + wid * 8 + lane;
    if (active) {
        int p = pos[b * NN + i];
        float xi = val[p];
        int g0 = gs[p], g1 = ge[p];
        if (g1 - g0 >= KK) {
#pragma unroll
            for (int r = 0; r < KK; ++r) win[r] = idx[g0 + r];
            bool in_top = (p - g0) < KK;
            if (!in_top) win[KK - 1] = i;
        } else {
            int cnt = 0;
            for (int q = g0; q < g1; ++q) win[cnt++] = idx[q];
            int L = g0 - 1, R = g1;
            while (cnt < KK) {
                float dL = (L >= 0) ? xi - val[L] : __builtin_inff();
                float dR = (R < NN) ? val[R] - xi : __builtin_inff();
                float dm = fminf(dL, dR);
                int La = NN, Lb = -1, Ra = NN, Rb = -1;
                if (dL == dm) {
                    Lb = L; La = gs[L];
                    while (La - 1 >= 0 && (xi - val[La - 1]) == dm) La = gs[La - 1];
                }
                if (dR == dm) {
                    Ra = R; Rb = ge[R] - 1;
                    while (Rb + 1 < NN && (val[Rb + 1] - xi) == dm) Rb = ge[Rb + 1] - 1;
                }
                bool oneL = (Lb >= 0) && (Rb < 0) && (La == gs[Lb]);
                bool oneR = (Rb >= 0) && (Lb < 0) && (Rb == ge[Ra] - 1);
                if (oneL) {
                    for (int q = La; q <= Lb && cnt < KK; ++q) win[cnt++] = idx[q];
                } else if (oneR) {
                    for (int q = Ra; q <= Rb && cnt < KK; ++q) win[cnt++] = idx[q];
                } else {
                    int last = -1;
                    while (cnt < KK) {
                        int best = 0x7fffffff;
                        for (int q = La; q <= Lb; ++q) { int jj = idx[q]; if (jj > last && jj < best) best = jj; }
                        for (int q = Ra; q <= Rb; ++q) { int jj = idx[q]; if (jj > last && jj < best) best = jj; }
                        if (best == 0x7fffffff) break;
                        win[cnt++] = best; last = best;
                    }
                }
                if (Lb >= 0) L = La - 1;
                if (Rb >= 0) R = Rb + 1;
            }
        }
#pragma unroll
        for (int r = 0; r < KK; ++r) {
            topk[(size_t)(b * NN + i) * KK + r] = win[r];
            atomicAdd(&hist[win[r]], 1);
        }
    }
    __syncthreads();
    for (int p = tid; p < NN; p += 256) {
        int h = hist[p];
        if (h) atomicAdd(&DV[b * NN + p], h);
    }
}

// ---------------------------------------------------------------------------
// Kernel 5: per batch, exclusive scan of DV -> CSR cursor init, fused dv2.
// ---------------------------------------------------------------------------
__global__ void __launch_bounds__(256) scan_kernel(const int* __restrict__ DV,
                                                   int* __restrict__ cursor,
                                                   float* __restrict__ dv2) {
    __shared__ int sums[256];
    int b = blockIdx.x, tid = threadIdx.x;
    int loc[7]; int s = 0;
#pragma unroll
    for (int e = 0; e < 7; ++e) {
        int p = tid * 7 + e;
        int v = (p < NN) ? DV[b * NN + p] : 0;
        loc[e] = s; s += v;
    }
    sums[tid] = s;
    __syncthreads();
    for (int off = 1; off < 256; off <<= 1) {
        int v = (tid >= off) ? sums[tid - off] : 0;
        __syncthreads();
        sums[tid] += v;
        __syncthreads();
    }
    int base = ((tid > 0) ? sums[tid - 1] : 0) + b * EPB;
#pragma unroll
    for (int e = 0; e < 7; ++e) {
        int p = tid * 7 + e;
        if (p < NN) {
            cursor[b * NN + p] = base + loc[e];
            dv2[b * NN + p] = 1.0f / sqrtf((float)DV[b * NN + p]);
        }
    }
}

// ---------------------------------------------------------------------------
// Kernel 6: fused {CSR fill (blocks 0..499)} and {lin layer-1 (blocks 500..899)}.
// ---------------------------------------------------------------------------
__global__ void __launch_bounds__(256) filllin_kernel(const int* __restrict__ topk,
                                                      int* __restrict__ cursor,
                                                      int* __restrict__ inv_pack,
                                                      const float* __restrict__ in,
                                                      const float* __restrict__ W,
                                                      const float* __restrict__ bias,
                                                      const float* __restrict__ dv2,
                                                      float* __restrict__ outP) {
    __shared__ float Wl[CC * CC];
    __shared__ float bl[CC];
    int blk = blockIdx.x, tid = threadIdx.x;
    if (blk < 500) {
        // ---- CSR fill: inv_pack[slot] = (vertex<<17)|edge ----
        int gid = blk * 256 + tid;
        if (gid < ROWS * KK) {
            int row = gid / KK;          // global edge id
            int b = row / NN;
            int v = b * NN + topk[gid];  // global vertex id
            int slot = atomicAdd(&cursor[v], 1);
            inv_pack[slot] = (v << 17) | row;
        }
        return;
    }
    // ---- lin layer 1 (transform=0): P[row,c] = 0.1*dv2[row]*(x_row@W + b)[c]
    for (int t = tid; t < CC * CC; t += 256) Wl[t] = W[t];
    if (tid < CC) bl[tid] = bias[tid];
    __syncthreads();
    int lane = tid & 63, wid = tid >> 6;
    int gw = (blk - 500) * 4 + wid;
    int nw = 400 * 4;
    for (int row = gw; row < ROWS; row += nw) {
        float d = dv2[row];
        float vin = in[(size_t)row * CC + lane];
        int vbits = __float_as_int(vin);
        float acc = bl[lane];
#pragma unroll
        for (int kk = 0; kk < CC; ++kk) {
            float xv = __int_as_float(__builtin_amdgcn_readlane(vbits, kk));
            acc = fmaf(xv, Wl[kk * CC + lane], acc);
        }
        outP[(size_t)row * CC + lane] = 0.1f * d * acc;
    }
}

// ---------------------------------------------------------------------------
// Kernel 7: P[row,c] = 0.1 * dv2[row] * ( in_row @ W + bias )[c]
// transform=1: in_row[c] := relu(dv2[row] * in[row,c])   (layer 2)
// ---------------------------------------------------------------------------
__global__ void __launch_bounds__(256) lin_kernel(const float* __restrict__ in,
                                                  const float* __restrict__ W,
                                                  const float* __restrict__ bias,
                                                  const float* __restrict__ dv2,
                                                  float* __restrict__ outP, int transform) {
    __shared__ float Wl[CC * CC];
    __shared__ float bl[CC];
    int tid = threadIdx.x;
    for (int t = tid; t < CC * CC; t += 256) Wl[t] = W[t];
    if (tid < CC) bl[tid] = bias[tid];
    __syncthreads();
    int lane = tid & 63, wid = tid >> 6;
    int gw = blockIdx.x * 4 + wid;
    int nw = gridDim.x * 4;
    for (int row = gw; row < ROWS; row += nw) {
        float d = dv2[row];
        float vin = in[(size_t)row * CC + lane];
        if (transform) vin = fmaxf(d * vin, 0.f);
        int vbits = __float_as_int(vin);
        float acc = bl[lane];
#pragma unroll
        for (int kk = 0; kk < CC; ++kk) {
            float xv = __int_as_float(__builtin_amdgcn_readlane(vbits, kk));
            acc = fmaf(xv, Wl[kk * CC + lane], acc);
        }
        outP[(size_t)row * CC + lane] = 0.1f * d * acc;
    }
}

// ---------------------------------------------------------------------------
// Kernel 8: z[e,c] = sum_t P[v_t(e), c]   (pure gather, one wave per edge)
// ---------------------------------------------------------------------------
__global__ void __launch_bounds__(256) zedge_kernel(const float* __restrict__ P,
                                                    const int* __restrict__ topk,
                                                    float* __restrict__ z) {
    int wid = threadIdx.x >> 6, lane = threadIdx.x & 63;
    int e = blockIdx.x * 4 + wid;
    if (e >= ROWS) return;
    int b = e / NN;
    const int* tk = topk + e * KK;
    int v[KK];
#pragma unroll
    for (int t = 0; t < KK; ++t) v[t] = tk[t];
    float acc = 0.f;
#pragma unroll
    for (int t = 0; t < KK; ++t) acc += P[((size_t)b * NN + v[t]) * CC + lane];
    z[(size_t)e * CC + lane] = acc;
}

// ---------------------------------------------------------------------------
// Kernel 9: flat segmented gather over the CSR membership list (GE=16).
// ---------------------------------------------------------------------------
__global__ void __launch_bounds__(256) gather2_kernel(const float* __restrict__ z,
                                                      const int* __restrict__ inv_pack,
                                                      float* __restrict__ Acc) {
    int wid = threadIdx.x >> 6, lane = threadIdx.x & 63;
    int w = blockIdx.x * 4 + wid;          // 0..7999
    int base = w * GE;
    int pk_l = inv_pack[base + (lane & 15)];
    int eid[GE], own[GE];
#pragma unroll
    for (int t = 0; t < GE; ++t) {
        int pk = __builtin_amdgcn_readlane(pk_l, t);
        eid[t] = pk & 0x1ffff;
        own[t] = pk >> 17;
    }
    float val[GE];
#pragma unroll
    for (int t = 0; t < GE; ++t) val[t] = z[(size_t)eid[t] * CC + lane];
    float acc = val[0];
    int cur = own[0];
#pragma unroll
    for (int t = 1; t < GE; ++t) {
        if (own[t] != cur) {                // wave-uniform branch
            atomicAdd(&Acc[(size_t)cur * CC + lane], acc);
            cur = own[t]; acc = val[t];
        } else acc += val[t];
    }
    atomicAdd(&Acc[(size_t)cur * CC + lane], acc);
}

// ---------------------------------------------------------------------------
// Kernel 10: final conv + relu + per-batch sum. (out pre-zeroed)
// ---------------------------------------------------------------------------
__global__ void final_kernel(const float* __restrict__ Acc, const float* __restrict__ dv2,
                             const float* __restrict__ w, const float* __restrict__ bsc,
                             float* __restrict__ out) {
    __shared__ float red[256];
    int blk = blockIdx.x;
    int b = blk >> 3, chunk = blk & 7;
    int tid = threadIdx.x;
    float local = 0.f;
    if (tid < 200) {
        int n = chunk * 200 + tid;
        int q = n >> 6, r = n & 63;
        float acc = bsc[0];
#pragma unroll 8
        for (int c = 0; c < CC; ++c) {
            int rowl = c * 25 + q;
            float v = Acc[((size_t)b * NN + rowl) * CC + r];
            float h = fmaxf(dv2[b * NN + rowl] * v, 0.f);
            acc = fmaf(h, w[c], acc);
        }
        local = fmaxf(acc, 0.f);
    }
    red[tid] = local; __syncthreads();
    for (int s = 128; s > 0; s >>= 1) { if (tid < s) red[tid] += red[tid + s]; __syncthreads(); }
    if (tid == 0) atomicAdd(&out[b], red[0]);
}

// ---------------------------------------------------------------------------
extern "C" void kernel_launch(void* const* d_in, const int* in_sizes, int n_in,
                              void* d_out, int out_size, void* d_ws, size_t ws_size,
                              hipStream_t stream) {
    const float* x      = (const float*)d_in[0];
    const float* w_con1 = (const float*)d_in[1];
    const float* b_con1 = (const float*)d_in[2];
    const float* W1     = (const float*)d_in[3];
    const float* b1     = (const float*)d_in[4];
    const float* W2     = (const float*)d_in[5];
    const float* b2     = (const float*)d_in[6];
    const float* w_con2 = (const float*)d_in[7];
    const float* b_con2 = (const float*)d_in[8];

    char* ws = (char*)d_ws;
    float* xx       = (float*)(ws + 0);         //  51200
    float* dv2      = (float*)(ws + 51200);     //  51200
    int*   DV       = (int*)  (ws + 102400);    //  51200
    float* pre      = (float*)(ws + 153600);    //  51200 (cursor aliases after softmax)
    int*   cursor   = (int*)  (ws + 153600);
    int*   topk     = (int*)  (ws + 204800);    // 512000
    float* buf0     = (float*)(ws + 716800);    // 3276800
    float* buf1     = (float*)(ws + 3993600);   // 3276800
    int*   inv_pack = (int*)  (ws + 7270400);   // 512000
    float* buf2     = (float*)(ws + 7782400);   // 3276800 (Acc1, pre-zeroed)
    float* buf3     = (float*)(ws + 11059200);  // 3276800 (Acc2, pre-zeroed)
    // sort scratch aliases buf0 (dead before lin1):
    float* sval = (float*)(ws + 716800);
    int*   sidx = (int*)  (ws + 716800 + 51200);
    int*   gst  = (int*)  (ws + 716800 + 102400);
    int*   gen  = (int*)  (ws + 716800 + 153600);
    int*   pos  = (int*)  (ws + 716800 + 204800);

    float* out = (float*)d_out;

    // Fused: zero Acc1+Acc2 (409600 float4), DV, out  +  conv_relu -> pre.
    zeroconv_kernel<<<1650, 256, 0, stream>>>((float4*)buf2, 409600, (int4*)DV, out,
                                              x, w_con1, b_con1, pre);
    softmax_kernel<<<BB, 256, 0, stream>>>(pre, xx);

    rank_kernel<<<ROWS / 4, 256, 0, stream>>>(xx, sval, sidx, gst, gen, pos);
    walk_kernel<<<400, 256, 0, stream>>>(sval, sidx, gst, gen, pos, topk, DV);
    scan_kernel<<<BB, 256, 0, stream>>>(DV, cursor, dv2);

    // Fused: CSR fill (500 blocks) + lin layer-1 (400 blocks) -> P1=buf0
    filllin_kernel<<<900, 256, 0, stream>>>(topk, cursor, inv_pack,
                                            x, W1, b1, dv2, buf0);

    // Layer 1: z1=buf1, Acc1=buf2
    zedge_kernel<<<ROWS / 4, 256, 0, stream>>>(buf0, topk, buf1);
    gather2_kernel<<<(ROWS * KK / GE) / 4, 256, 0, stream>>>(buf1, inv_pack, buf2);

    // Layer 2: P2=buf0, z2=buf1, Acc2=buf3
    lin_kernel<<<400, 256, 0, stream>>>(buf2, W2, b2, dv2, buf0, 1);
    zedge_kernel<<<ROWS / 4, 256, 0, stream>>>(buf0, topk, buf1);
    gather2_kernel<<<(ROWS * KK / GE) / 4, 256, 0, stream>>>(buf1, inv_pack, buf3);

    final_kernel<<<64, 256, 0, stream>>>(buf3, dv2, w_con2, b_con2, out);
}

// Round 17
// 119.184 us; speedup vs baseline: 1.1486x; 1.0251x over previous
//
#include <hip/hip_runtime.h>
#include <math.h>

#define NN 1600      // H*W
#define BB 8         // batch
#define CC 64        // channels
#define KK 10        // top-k
#define ROWS (BB*NN) // 12800
#define EPB (NN*KK)  // edge-memberships per batch = 16000
#define GE 16        // memberships per wave in gather2

// ---------------------------------------------------------------------------
// Kernel 1 (stage A): three independent block-ranges:
//   [0,1600):    zero Acc1+Acc2 (contiguous), DV, out
//   [1600,1650): conv_relu  pre[b,n] = relu(sum_c x[b,c,n]*w[c] + b0)
//   [1650,2050): Q1[row,c] = x_row @ W1 + b1   (NO dv2 scale - applied later)
// All mutually independent -> full width, no added serial stage.
// ---------------------------------------------------------------------------
__global__ void __launch_bounds__(256) stageA_kernel(float4* __restrict__ accs, int n4,
                                                     int4* __restrict__ DV4, float* __restrict__ out,
                                                     const float* __restrict__ x,
                                                     const float* __restrict__ w,
                                                     const float* __restrict__ bsc,
                                                     float* __restrict__ pre,
                                                     const float* __restrict__ W1,
                                                     const float* __restrict__ b1,
                                                     float* __restrict__ Q1) {
    __shared__ float Wl[CC * CC];
    __shared__ float bl[CC];
    int blk = blockIdx.x, tid = threadIdx.x;
    if (blk < 1600) {
        int gid = blk * 256 + tid;
        if (gid < n4) accs[gid] = make_float4(0.f, 0.f, 0.f, 0.f);
        if (gid < ROWS / 4) DV4[gid] = make_int4(0, 0, 0, 0);
        if (gid < BB) out[gid] = 0.f;
        return;
    }
    if (blk < 1650) {
        int gid = (blk - 1600) * 256 + tid;
        if (gid >= ROWS) return;
        int b = gid / NN, n = gid % NN;
        const float* xb = x + (size_t)b * CC * NN;
        float acc = bsc[0];
#pragma unroll 16
        for (int c = 0; c < CC; ++c) acc = fmaf(xb[(size_t)c * NN + n], w[c], acc);
        pre[gid] = fmaxf(acc, 0.f);
        return;
    }
    // ---- Q1 = x @ W1 + b1 (unscaled lin layer 1) ----
    for (int t = tid; t < CC * CC; t += 256) Wl[t] = W1[t];
    if (tid < CC) bl[tid] = b1[tid];
    __syncthreads();
    int lane = tid & 63, wid = tid >> 6;
    int gw = (blk - 1650) * 4 + wid;
    int nw = 400 * 4;
    for (int row = gw; row < ROWS; row += nw) {
        float vin = x[(size_t)row * CC + lane];
        int vbits = __float_as_int(vin);
        float acc = bl[lane];
#pragma unroll
        for (int kk = 0; kk < CC; ++kk) {
            float xv = __int_as_float(__builtin_amdgcn_readlane(vbits, kk));
            acc = fmaf(xv, Wl[kk * CC + lane], acc);
        }
        Q1[(size_t)row * CC + lane] = acc;
    }
}

// ---------------------------------------------------------------------------
// Kernel 2: xx[b,:] = softmax(pre[b,:])
// ---------------------------------------------------------------------------
__global__ void softmax_kernel(const float* __restrict__ pre, float* __restrict__ xx) {
    __shared__ float xs[NN];
    __shared__ float red[256];
    int b = blockIdx.x, tid = threadIdx.x;
    for (int n = tid; n < NN; n += 256) xs[n] = pre[b * NN + n];
    __syncthreads();
    float m = -1e30f;
    for (int n = tid; n < NN; n += 256) m = fmaxf(m, xs[n]);
    red[tid] = m; __syncthreads();
    for (int s = 128; s > 0; s >>= 1) { if (tid < s) red[tid] = fmaxf(red[tid], red[tid + s]); __syncthreads(); }
    float mx = red[0]; __syncthreads();
    float ls = 0.f;
    for (int n = tid; n < NN; n += 256) { float e = expf(xs[n] - mx); xs[n] = e; ls += e; }
    red[tid] = ls; __syncthreads();
    for (int s = 128; s > 0; s >>= 1) { if (tid < s) red[tid] += red[tid + s]; __syncthreads(); }
    float S = red[0];
    for (int n = tid; n < NN; n += 256) xx[b * NN + n] = xs[n] / S;
}

// ---------------------------------------------------------------------------
// Kernel 3: rank-by-count "sort" (bit-identical to a stable (value,idx) sort).
// ---------------------------------------------------------------------------
__global__ void __launch_bounds__(256) rank_kernel(const float* __restrict__ xx,
                                                   float* __restrict__ sval, int* __restrict__ sidx,
                                                   int* __restrict__ gst, int* __restrict__ gen,
                                                   int* __restrict__ pos) {
    __shared__ float xs[NN];
    int tid = threadIdx.x;
    int wid = tid >> 6, lane = tid & 63;
    int row = blockIdx.x * 4 + wid;     // all 4 rows share one batch
    int b = row / NN, i = row % NN;
    for (int t = tid; t < NN; t += 256) xs[t] = xx[b * NN + t];
    __syncthreads();
    float xi = xs[i];
    int strict = 0, eq_total = 0, eq_before = 0;
#pragma unroll 5
    for (int s = 0; s < 25; ++s) {
        int j = lane + 64 * s;
        float vj = xs[j];
        unsigned long long blt = __ballot(vj < xi);
        unsigned long long beq = __ballot(vj == xi);
        unsigned long long bbf = __ballot(vj == xi && j < i);
        strict    += __popcll(blt);
        eq_total  += __popcll(beq);
        eq_before += __popcll(bbf);
    }
    if (lane == 0) {
        int rank = strict + eq_before;
        sval[b * NN + rank] = xi;
        sidx[b * NN + rank] = i;
        gst[b * NN + rank] = strict;
        gen[b * NN + rank] = strict + eq_total;
        pos[b * NN + i] = rank;
    }
}

// ---------------------------------------------------------------------------
// Kernel 4: walk the sorted array -> exact stable top-10 per row + DV.
// 400 blocks = 50 chunks x 8 batches; 32 rows/block across 4 waves.
// ---------------------------------------------------------------------------
__global__ void __launch_bounds__(256) walk_kernel(const float* __restrict__ sval,
                                                   const int* __restrict__ sidx,
                                                   const int* __restrict__ gst,
                                                   const int* __restrict__ gen,
                                                   const int* __restrict__ pos,
                                                   int* __restrict__ topk, int* __restrict__ DV) {
    __shared__ float val[NN];
    __shared__ int   idx[NN];
    __shared__ int   gs[NN];
    __shared__ int   ge[NN];
    __shared__ int   hist[NN];
    int blk = blockIdx.x;
    int b = blk / 50, chunk = blk % 50;
    int tid = threadIdx.x;
    for (int p = tid; p < NN; p += 256) {
        val[p] = sval[b * NN + p];
        idx[p] = sidx[b * NN + p];
        gs[p]  = gst[b * NN + p];
        ge[p]  = gen[b * NN + p];
        hist[p] = 0;
    }
    __syncthreads();
    int win[KK];
    int wid = tid >> 6, lane = tid & 63;
    bool active = lane < 8;
    int i = chunk * 32 + wid * 8 + lane;
    if (active) {
        int p = pos[b * NN + i];
        float xi = val[p];
        int g0 = gs[p], g1 = ge[p];
        if (g1 - g0 >= KK) {
#pragma unroll
            for (int r = 0; r < KK; ++r) win[r] = idx[g0 + r];
            bool in_top = (p - g0) < KK;
            if (!in_top) win[KK - 1] = i;
        } else {
            int cnt = 0;
            for (int q = g0; q < g1; ++q) win[cnt++] = idx[q];
            int L = g0 - 1, R = g1;
            while (cnt < KK) {
                float dL = (L >= 0) ? xi - val[L] : __builtin_inff();
                float dR = (R < NN) ? val[R] - xi : __builtin_inff();
                float dm = fminf(dL, dR);
                int La = NN, Lb = -1, Ra = NN, Rb = -1;
                if (dL == dm) {
                    Lb = L; La = gs[L];
                    while (La - 1 >= 0 && (xi - val[La - 1]) == dm) La = gs[La - 1];
                }
                if (dR == dm) {
                    Ra = R; Rb = ge[R] - 1;
                    while (Rb + 1 < NN && (val[Rb + 1] - xi) == dm) Rb = ge[Rb + 1] - 1;
                }
                bool oneL = (Lb >= 0) && (Rb < 0) && (La == gs[Lb]);
                bool oneR = (Rb >= 0) && (Lb < 0) && (Rb == ge[Ra] - 1);
                if (oneL) {
                    for (int q = La; q <= Lb && cnt < KK; ++q) win[cnt++] = idx[q];
                } else if (oneR) {
                    for (int q = Ra; q <= Rb && cnt < KK; ++q) win[cnt++] = idx[q];
                } else {
                    int last = -1;
                    while (cnt < KK) {
                        int best = 0x7fffffff;
                        for (int q = La; q <= Lb; ++q) { int jj = idx[q]; if (jj > last && jj < best) best = jj; }
                        for (int q = Ra; q <= Rb; ++q) { int jj = idx[q]; if (jj > last && jj < best) best = jj; }
                        if (best == 0x7fffffff) break;
                        win[cnt++] = best; last = best;
                    }
                }
                if (Lb >= 0) L = La - 1;
                if (Rb >= 0) R = Rb + 1;
            }
        }
#pragma unroll
        for (int r = 0; r < KK; ++r) {
            topk[(size_t)(b * NN + i) * KK + r] = win[r];
            atomicAdd(&hist[win[r]], 1);
        }
    }
    __syncthreads();
    for (int p = tid; p < NN; p += 256) {
        int h = hist[p];
        if (h) atomicAdd(&DV[b * NN + p], h);
    }
}

// ---------------------------------------------------------------------------
// Kernel 5: per batch, exclusive scan of DV -> CSR cursor init, fused dv2.
// ---------------------------------------------------------------------------
__global__ void __launch_bounds__(256) scan_kernel(const int* __restrict__ DV,
                                                   int* __restrict__ cursor,
                                                   float* __restrict__ dv2) {
    __shared__ int sums[256];
    int b = blockIdx.x, tid = threadIdx.x;
    int loc[7]; int s = 0;
#pragma unroll
    for (int e = 0; e < 7; ++e) {
        int p = tid * 7 + e;
        int v = (p < NN) ? DV[b * NN + p] : 0;
        loc[e] = s; s += v;
    }
    sums[tid] = s;
    __syncthreads();
    for (int off = 1; off < 256; off <<= 1) {
        int v = (tid >= off) ? sums[tid - off] : 0;
        __syncthreads();
        sums[tid] += v;
        __syncthreads();
    }
    int base = ((tid > 0) ? sums[tid - 1] : 0) + b * EPB;
#pragma unroll
    for (int e = 0; e < 7; ++e) {
        int p = tid * 7 + e;
        if (p < NN) {
            cursor[b * NN + p] = base + loc[e];
            dv2[b * NN + p] = 1.0f / sqrtf((float)DV[b * NN + p]);
        }
    }
}

// ---------------------------------------------------------------------------
// Kernel 6: fused {CSR fill (blocks 0..499)} and {zedge layer-1 (blocks 500+)}.
// Both depend only on {walk, scan, stage A} outputs - mutually independent.
// zedge1': z1[e,c] = sum_t (0.1*dv2[v_t]) * Q1[v_t,c]  (bit-identical to the
// old per-row P1 = (0.1*dv2)*Q1 then summed: same grouping, same order).
// ---------------------------------------------------------------------------
__global__ void __launch_bounds__(256) fillzedge_kernel(const int* __restrict__ topk,
                                                        int* __restrict__ cursor,
                                                        int* __restrict__ inv_pack,
                                                        const float* __restrict__ Q1,
                                                        const float* __restrict__ dv2,
                                                        float* __restrict__ z) {
    int blk = blockIdx.x, tid = threadIdx.x;
    if (blk < 500) {
        // ---- CSR fill: inv_pack[slot] = (vertex<<17)|edge ----
        int gid = blk * 256 + tid;
        if (gid < ROWS * KK) {
            int row = gid / KK;          // global edge id
            int b = row / NN;
            int v = b * NN + topk[gid];  // global vertex id
            int slot = atomicAdd(&cursor[v], 1);
            inv_pack[slot] = (v << 17) | row;
        }
        return;
    }
    // ---- zedge layer 1 with fused scale ----
    int wid = tid >> 6, lane = tid & 63;
    int e = (blk - 500) * 4 + wid;
    if (e >= ROWS) return;
    int b = e / NN;
    const int* tk = topk + e * KK;
    int v[KK];
#pragma unroll
    for (int t = 0; t < KK; ++t) v[t] = tk[t];
    float acc = 0.f;
#pragma unroll
    for (int t = 0; t < KK; ++t) {
        int gv = b * NN + v[t];
        float d = dv2[gv];
        acc += (0.1f * d) * Q1[(size_t)gv * CC + lane];
    }
    z[(size_t)e * CC + lane] = acc;
}

// ---------------------------------------------------------------------------
// Kernel 7: P[row,c] = 0.1 * dv2[row] * ( in_row @ W + bias )[c]
// transform=1: in_row[c] := relu(dv2[row] * in[row,c])   (layer 2)
// ---------------------------------------------------------------------------
__global__ void __launch_bounds__(256) lin_kernel(const float* __restrict__ in,
                                                  const float* __restrict__ W,
                                                  const float* __restrict__ bias,
                                                  const float* __restrict__ dv2,
                                                  float* __restrict__ outP, int transform) {
    __shared__ float Wl[CC * CC];
    __shared__ float bl[CC];
    int tid = threadIdx.x;
    for (int t = tid; t < CC * CC; t += 256) Wl[t] = W[t];
    if (tid < CC) bl[tid] = bias[tid];
    __syncthreads();
    int lane = tid & 63, wid = tid >> 6;
    int gw = blockIdx.x * 4 + wid;
    int nw = gridDim.x * 4;
    for (int row = gw; row < ROWS; row += nw) {
        float d = dv2[row];
        float vin = in[(size_t)row * CC + lane];
        if (transform) vin = fmaxf(d * vin, 0.f);
        int vbits = __float_as_int(vin);
        float acc = bl[lane];
#pragma unroll
        for (int kk = 0; kk < CC; ++kk) {
            float xv = __int_as_float(__builtin_amdgcn_readlane(vbits, kk));
            acc = fmaf(xv, Wl[kk * CC + lane], acc);
        }
        outP[(size_t)row * CC + lane] = 0.1f * d * acc;
    }
}

// ---------------------------------------------------------------------------
// Kernel 8: z[e,c] = sum_t P[v_t(e), c]   (layer 2, P pre-scaled)
// ---------------------------------------------------------------------------
__global__ void __launch_bounds__(256) zedge_kernel(const float* __restrict__ P,
                                                    const int* __restrict__ topk,
                                                    float* __restrict__ z) {
    int wid = threadIdx.x >> 6, lane = threadIdx.x & 63;
    int e = blockIdx.x * 4 + wid;
    if (e >= ROWS) return;
    int b = e / NN;
    const int* tk = topk + e * KK;
    int v[KK];
#pragma unroll
    for (int t = 0; t < KK; ++t) v[t] = tk[t];
    float acc = 0.f;
#pragma unroll
    for (int t = 0; t < KK; ++t) acc += P[((size_t)b * NN + v[t]) * CC + lane];
    z[(size_t)e * CC + lane] = acc;
}

// ---------------------------------------------------------------------------
// Kernel 9: flat segmented gather over the CSR membership list (GE=16).
// ---------------------------------------------------------------------------
__global__ void __launch_bounds__(256) gather2_kernel(const float* __restrict__ z,
                                                      const int* __restrict__ inv_pack,
                                                      float* __restrict__ Acc) {
    int wid = threadIdx.x >> 6, lane = threadIdx.x & 63;
    int w = blockIdx.x * 4 + wid;          // 0..7999
    int base = w * GE;
    int pk_l = inv_pack[base + (lane & 15)];
    int eid[GE], own[GE];
#pragma unroll
    for (int t = 0; t < GE; ++t) {
        int pk = __builtin_amdgcn_readlane(pk_l, t);
        eid[t] = pk & 0x1ffff;
        own[t] = pk >> 17;
    }
    float val[GE];
#pragma unroll
    for (int t = 0; t < GE; ++t) val[t] = z[(size_t)eid[t] * CC + lane];
    float acc = val[0];
    int cur = own[0];
#pragma unroll
    for (int t = 1; t < GE; ++t) {
        if (own[t] != cur) {                // wave-uniform branch
            atomicAdd(&Acc[(size_t)cur * CC + lane], acc);
            cur = own[t]; acc = val[t];
        } else acc += val[t];
    }
    atomicAdd(&Acc[(size_t)cur * CC + lane], acc);
}

// ---------------------------------------------------------------------------
// Kernel 10: final conv + relu + per-batch sum. (out pre-zeroed)
// ---------------------------------------------------------------------------
__global__ void final_kernel(const float* __restrict__ Acc, const float* __restrict__ dv2,
                             const float* __restrict__ w, const float* __restrict__ bsc,
                             float* __restrict__ out) {
    __shared__ float red[256];
    int blk = blockIdx.x;
    int b = blk >> 3, chunk = blk & 7;
    int tid = threadIdx.x;
    float local = 0.f;
    if (tid < 200) {
        int n = chunk * 200 + tid;
        int q = n >> 6, r = n & 63;
        float acc = bsc[0];
#pragma unroll 8
        for (int c = 0; c < CC; ++c) {
            int rowl = c * 25 + q;
            float v = Acc[((size_t)b * NN + rowl) * CC + r];
            float h = fmaxf(dv2[b * NN + rowl] * v, 0.f);
            acc = fmaf(h, w[c], acc);
        }
        local = fmaxf(acc, 0.f);
    }
    red[tid] = local; __syncthreads();
    for (int s = 128; s > 0; s >>= 1) { if (tid < s) red[tid] += red[tid + s]; __syncthreads(); }
    if (tid == 0) atomicAdd(&out[b], red[0]);
}

// ---------------------------------------------------------------------------
extern "C" void kernel_launch(void* const* d_in, const int* in_sizes, int n_in,
                              void* d_out, int out_size, void* d_ws, size_t ws_size,
                              hipStream_t stream) {
    const float* x      = (const float*)d_in[0];
    const float* w_con1 = (const float*)d_in[1];
    const float* b_con1 = (const float*)d_in[2];
    const float* W1     = (const float*)d_in[3];
    const float* b1     = (const float*)d_in[4];
    const float* W2     = (const float*)d_in[5];
    const float* b2     = (const float*)d_in[6];
    const float* w_con2 = (const float*)d_in[7];
    const float* b_con2 = (const float*)d_in[8];

    char* ws = (char*)d_ws;
    float* xx       = (float*)(ws + 0);         //  51200
    float* dv2      = (float*)(ws + 51200);     //  51200
    int*   DV       = (int*)  (ws + 102400);    //  51200
    float* pre      = (float*)(ws + 153600);    //  51200 (cursor aliases after softmax)
    int*   cursor   = (int*)  (ws + 153600);
    int*   topk     = (int*)  (ws + 204800);    // 512000
    float* buf0     = (float*)(ws + 716800);    // 3276800
    float* buf1     = (float*)(ws + 3993600);   // 3276800
    int*   inv_pack = (int*)  (ws + 7270400);   // 512000
    float* buf2     = (float*)(ws + 7782400);   // 3276800 (Acc1, pre-zeroed)
    float* buf3     = (float*)(ws + 11059200);  // 3276800 (Acc2, pre-zeroed)
    float* Q1       = (float*)(ws + 14336000);  // 3276800 (unscaled lin1 output)
    // sort scratch aliases buf0 (dead before lin2 writes buf0):
    float* sval = (float*)(ws + 716800);
    int*   sidx = (int*)  (ws + 716800 + 51200);
    int*   gst  = (int*)  (ws + 716800 + 102400);
    int*   gen  = (int*)  (ws + 716800 + 153600);
    int*   pos  = (int*)  (ws + 716800 + 204800);

    float* out = (float*)d_out;

    // Stage A: zero Acc1+Acc2+DV+out (1600 blks) | conv->pre (50) | Q1 (400)
    stageA_kernel<<<2050, 256, 0, stream>>>((float4*)buf2, 409600, (int4*)DV, out,
                                            x, w_con1, b_con1, pre, W1, b1, Q1);
    softmax_kernel<<<BB, 256, 0, stream>>>(pre, xx);

    rank_kernel<<<ROWS / 4, 256, 0, stream>>>(xx, sval, sidx, gst, gen, pos);
    walk_kernel<<<400, 256, 0, stream>>>(sval, sidx, gst, gen, pos, topk, DV);
    scan_kernel<<<BB, 256, 0, stream>>>(DV, cursor, dv2);

    // Fused: CSR fill (500 blocks) | zedge layer-1 with fused 0.1*dv2 scale
    fillzedge_kernel<<<500 + ROWS / 4, 256, 0, stream>>>(topk, cursor, inv_pack,
                                                         Q1, dv2, buf1);
    // Layer 1 gather: Acc1=buf2
    gather2_kernel<<<(ROWS * KK / GE) / 4, 256, 0, stream>>>(buf1, inv_pack, buf2);

    // Layer 2: P2=buf0, z2=buf1, Acc2=buf3
    lin_kernel<<<400, 256, 0, stream>>>(buf2, W2, b2, dv2, buf0, 1);
    zedge_kernel<<<ROWS / 4, 256, 0, stream>>>(buf0, topk, buf1);
    gather2_kernel<<<(ROWS * KK / GE) / 4, 256, 0, stream>>>(buf1, inv_pack, buf3);

    final_kernel<<<64, 256, 0, stream>>>(buf3, dv2, w_con2, b_con2, out);
}